// Round 4
// baseline (353.213 us; speedup 1.0000x reference)
//
#include <hip/hip_runtime.h>

#define NQ     12
#define DIM    4096
#define BATCH  4096
#define NGEN   2

typedef float f32x2 __attribute__((ext_vector_type(2)));

// ---------------- compile-time GF(2) ring-permutation tables ----------------
// Basis index b: wire w <-> bit position p = 11 - w  (C-order flatten of (2,)*12).
constexpr unsigned cnot_map(unsigned b, int c, int t) {
  return b ^ (((b >> c) & 1u) << t);
}
constexpr unsigned ring_fwd(unsigned b) {
  b = cnot_map(b, 0, 11);
  for (int y = 10; y >= 0; --y) b = cnot_map(b, 11 - y, 10 - y);
  return b;
}
constexpr unsigned ring_inv(unsigned b) {
  for (int y = 0; y <= 10; ++y) b = cnot_map(b, 11 - y, 10 - y);
  b = cnot_map(b, 0, 11);
  return b;
}
constexpr unsigned pw (unsigned b, int k) { for (int r = 0; r < k; ++r) b = ring_fwd(b); return b; }
constexpr unsigned pwi(unsigned b, int k) { for (int r = 0; r < k; ++r) b = ring_inv(b); return b; }
constexpr int parity12(unsigned x) { int p = 0; for (int j = 0; j < 12; ++j) p ^= (x >> j) & 1; return p; }

struct QT {
  unsigned short v[2][12];    // pairing vector: R^(li+1) e_p
  unsigned short c[2][12];    // selector mask:  row_p(R^-(li+1))
};
constexpr QT make_qt() {
  QT t{};
  for (int li = 0; li < 2; ++li)
    for (int y = 0; y < 12; ++y) {
      const int p = 11 - y;
      t.v[li][y] = (unsigned short)pw(1u << p, li + 1);
      unsigned cm = 0;
      for (int j = 0; j < 12; ++j)
        cm |= (unsigned)((pwi(1u << j, li + 1) >> p) & 1u) << j;
      t.c[li][y] = (unsigned short)cm;
    }
  return t;
}
constexpr QT qt = make_qt();

// parity(v_a & c_b) = delta_ab within a layer -> uniform per-thread orientation.
constexpr bool ortho_ok() {
  for (int li = 0; li < 2; ++li)
    for (int a = 0; a < 12; ++a)
      for (int b = 0; b < 12; ++b)
        if (parity12((unsigned)qt.v[li][a] & (unsigned)qt.c[li][b]) != (a == b ? 1 : 0))
          return false;
  if (ring_inv(ring_fwd(0xABCu)) != 0xABCu) return false;
  return true;
}
static_assert(ortho_ok(), "GF(2) orthogonality violated");

// Fixed LDS layout swizzle (linear, bijective).
constexpr unsigned A12(unsigned q) { return (q ^ (q >> 4) ^ (q >> 8)) & 0xFFFu; }

constexpr int msb12(unsigned x) { int m = -1; for (int i = 0; i < 12; ++i) if ((x >> i) & 1) m = i; return m; }
constexpr bool bins(unsigned* byMsb, unsigned x) {
  while (x) { int m = msb12(x); if (!byMsb[m]) { byMsb[m] = x; return true; } x ^= byMsb[m]; }
  return false;
}

// 6 passes (2 layers x 3 groups of 4 commuting gates).
struct GTab {
  unsigned lut[6][256];         // (pb << 16) | (A12(tbase) << 3)   [byte offset]
  unsigned short gv[6][16];     // A12(G(j)); constexpr immediates, <<3 at use
  unsigned short sflo[256];     // A12(R^3(tid))
  unsigned short sfhi[16];      // A12(R^3(k << 8)); constexpr immediates
  unsigned char ok;
};
constexpr GTab make_gtab() {
  GTab t{};
  bool good = true;
  for (int li = 0; li < 2; ++li)
    for (int gi = 0; gi < 3; ++gi) {
      const int gid = li * 3 + gi;
      unsigned v[4], cm[4];
      for (int b = 0; b < 4; ++b) { v[b] = qt.v[li][gi * 4 + b]; cm[b] = qt.c[li][gi * 4 + b]; }
      unsigned byMsb[12] = {};
      for (int b = 0; b < 4; ++b) if (!bins(byMsb, v[b])) good = false;
      int Tpos[8] = {}; int c = 0;
      for (int cand = 0; cand < 12 && c < 8; ++cand)
        if (bins(byMsb, 1u << cand)) Tpos[c++] = cand;
      if (c != 8) good = false;
      for (int tid = 0; tid < 256; ++tid) {
        unsigned q = 0;
        for (int cc = 0; cc < 8; ++cc) if ((tid >> cc) & 1) q ^= 1u << Tpos[cc];
        unsigned pb = 0;
        for (int b = 0; b < 4; ++b) pb |= (unsigned)parity12(q & cm[b]) << b;
        t.lut[gid][tid] = (pb << 16) | (A12(q) << 3);
      }
      for (int j = 0; j < 16; ++j) {
        unsigned g = 0;
        for (int b = 0; b < 4; ++b) if ((j >> b) & 1) g ^= v[b];
        t.gv[gid][j] = (unsigned short)A12(g);
      }
      bool seen[4096] = {};
      for (int tid = 0; tid < 256; ++tid)
        for (int j = 0; j < 16; ++j) {
          unsigned idx = ((t.lut[gid][tid] & 0xFFFFu) >> 3) ^ (unsigned)t.gv[gid][j];
          if (idx >= 4096 || seen[idx]) good = false;
          seen[idx] = true;
        }
    }
  for (int tid = 0; tid < 256; ++tid) t.sflo[tid] = (unsigned short)A12(pw((unsigned)tid, 3));
  for (int k = 0; k < 16; ++k)       t.sfhi[k]   = (unsigned short)A12(pw((unsigned)k << 8, 3));
  t.ok = good ? 1 : 0;
  return t;
}
constexpr GTab h_gtab = make_gtab();
static_assert(h_gtab.ok == 1, "group tables inconsistent");
__constant__ GTab d_gtab = make_gtab();

// ---------------- scalar complex helpers (setup only) ----------------
__device__ __forceinline__ float2 cmuls(float2 a, float2 b) {
  return make_float2(a.x * b.x - a.y * b.y, a.x * b.y + a.y * b.x);
}
__device__ __forceinline__ float2 cadds(float2 a, float2 b) {
  return make_float2(a.x + b.x, a.y + b.y);
}
__device__ __forceinline__ void mat2mul(const float2* A, const float2* B, float2* C) {
  C[0] = cadds(cmuls(A[0], B[0]), cmuls(A[1], B[2]));
  C[1] = cadds(cmuls(A[0], B[1]), cmuls(A[1], B[3]));
  C[2] = cadds(cmuls(A[2], B[0]), cmuls(A[3], B[2]));
  C[3] = cadds(cmuls(A[2], B[1]), cmuls(A[3], B[3]));
}
// U = RY(c)*RX(b)*RZ(a); SU(2): u11 = conj(u00), u10 = -conj(u01)
__device__ __forceinline__ void fusedU(float a, float b, float c, float2* U) {
  float sa, ca, sb, cb, sc, cc;
  sincosf(a * 0.5f, &sa, &ca);
  sincosf(b * 0.5f, &sb, &cb);
  sincosf(c * 0.5f, &sc, &cc);
  float2 RZ[4] = { {ca, -sa}, {0.f, 0.f}, {0.f, 0.f}, {ca, sa} };
  float2 RX[4] = { {cb, 0.f}, {0.f, -sb}, {0.f, -sb}, {cb, 0.f} };
  float2 RY[4] = { {cc, 0.f}, {-sc, 0.f}, {sc, 0.f}, {cc, 0.f} };
  float2 M[4];
  mat2mul(RX, RZ, M);
  mat2mul(RY, M, U);
}

__device__ __forceinline__ f32x2 pcmul(f32x2 a, f32x2 b) {
  return (f32x2){a.x, a.x} * b + (f32x2){-a.y, a.y} * (f32x2){b.y, b.x};
}
__device__ __forceinline__ float xorf(float f, unsigned m) {
  return __uint_as_float(__float_as_uint(f) ^ m);
}

// ---------------- VOP3P packed-f32 helpers (zero-mov butterfly) ----------------
// ga={ax,ay}, gb={bx,by}, q={ay',bx'} (sign-folded). Butterfly:
//  y0 = {ax*s0.x - ay'*s0.y + bx'*s1.x - by*s1.y,  ax*s0.y + ay'*s0.x + bx'*s1.y + by*s1.x}
//  y1 = {ax*s1.x + ay'*s1.y - bx'*s0.x - by*s0.y,  ax*s1.y - ay'*s1.x - bx'*s0.y + by*s0.x}
__device__ __forceinline__ f32x2 pk_mul_dl(f32x2 a, f32x2 b) {   // {a.lo*b.lo, a.lo*b.hi}
  f32x2 d;
  asm("v_pk_mul_f32 %0, %1, %2 op_sel:[0,0] op_sel_hi:[0,1]" : "=v"(d) : "v"(a), "v"(b));
  return d;
}
__device__ __forceinline__ f32x2 pk_f1(f32x2 a, f32x2 s, f32x2 c) {  // {-a.lo*s.hi, a.lo*s.lo} + c
  f32x2 d;
  asm("v_pk_fma_f32 %0, %1, %2, %3 op_sel:[0,1,0] op_sel_hi:[0,0,1] neg_lo:[1,0,0]"
      : "=v"(d) : "v"(a), "v"(s), "v"(c));
  return d;
}
__device__ __forceinline__ f32x2 pk_f1b(f32x2 a, f32x2 s, f32x2 c) { // {a.lo*s.hi, -a.lo*s.lo} + c
  f32x2 d;
  asm("v_pk_fma_f32 %0, %1, %2, %3 op_sel:[0,1,0] op_sel_hi:[0,0,1] neg_hi:[1,0,0]"
      : "=v"(d) : "v"(a), "v"(s), "v"(c));
  return d;
}
__device__ __forceinline__ f32x2 pk_f2(f32x2 a, f32x2 s, f32x2 c) {  // {a.hi*s.lo, a.hi*s.hi} + c
  f32x2 d;
  asm("v_pk_fma_f32 %0, %1, %2, %3 op_sel:[1,0,0] op_sel_hi:[1,1,1]"
      : "=v"(d) : "v"(a), "v"(s), "v"(c));
  return d;
}
__device__ __forceinline__ f32x2 pk_f2b(f32x2 a, f32x2 s, f32x2 c) { // {-a.hi*s.lo, -a.hi*s.hi} + c
  f32x2 d;
  asm("v_pk_fma_f32 %0, %1, %2, %3 op_sel:[1,0,0] op_sel_hi:[1,1,1] neg_lo:[1,0,0] neg_hi:[1,0,0]"
      : "=v"(d) : "v"(a), "v"(s), "v"(c));
  return d;
}
__device__ __forceinline__ f32x2 pk_f3(f32x2 a, f32x2 s, f32x2 c) {  // {-a.hi*s.hi, a.hi*s.lo} + c
  f32x2 d;
  asm("v_pk_fma_f32 %0, %1, %2, %3 op_sel:[1,1,0] op_sel_hi:[1,0,1] neg_lo:[1,0,0]"
      : "=v"(d) : "v"(a), "v"(s), "v"(c));
  return d;
}

// ---------------- one pass: 4 commuting gates on a 16-entry coset tile ----------------
template<int GID>
__device__ __forceinline__ void do_pass(f32x2* st, const f32x2 (*gAB)[2], unsigned L) {
  const unsigned tbB = L & 0xFFFFu;   // byte offset of coset base (A12-swizzled, <<3)
  const unsigned pb  = L >> 16;       // orientation bits for the 4 gates
  char* stb = (char*)st;

  f32x2 e[16];
  #pragma unroll
  for (int j = 0; j < 16; ++j)
    e[j] = *(const f32x2*)(stb + (tbB ^ ((unsigned)h_gtab.gv[GID][j] << 3)));

  constexpr int gbase = (GID / 3) * 12 + (GID % 3) * 4;
  #pragma unroll
  for (int b = 0; b < 4; ++b) {
    const f32x2 ga = gAB[gbase + b][0];   // {ax, ay}
    const f32x2 gb = gAB[gbase + b][1];   // {bx, by}
    const unsigned sg = ((pb >> b) & 1u) << 31;
    f32x2 q;
    q.x = xorf(ga.y, sg);                 // ay'
    q.y = xorf(gb.x, sg);                 // bx'
    #pragma unroll
    for (int j0 = 0; j0 < 16; ++j0) {
      if (j0 & (1 << b)) continue;
      const int j1 = j0 | (1 << b);
      const f32x2 s0 = e[j0], s1 = e[j1];
      f32x2 t0 = pk_mul_dl(ga, s0);       // ax * s0
      t0 = pk_f1(q, s0, t0);              // + {-ay'*s0.y,  ay'*s0.x}
      t0 = pk_f2(q, s1, t0);              // + { bx'*s1.x,  bx'*s1.y}
      t0 = pk_f3(gb, s1, t0);             // + {-by *s1.y,  by *s1.x}
      f32x2 t1 = pk_mul_dl(ga, s1);       // ax * s1
      t1 = pk_f1b(q, s1, t1);             // + { ay'*s1.y, -ay'*s1.x}
      t1 = pk_f2b(q, s0, t1);             // + {-bx'*s0.x, -bx'*s0.y}
      t1 = pk_f3(gb, s0, t1);             // + {-by *s0.y,  by *s0.x}
      e[j0] = t0;
      e[j1] = t1;
    }
  }
  #pragma unroll
  for (int j = 0; j < 16; ++j)
    *(f32x2*)(stb + (tbB ^ ((unsigned)h_gtab.gv[GID][j] << 3))) = e[j];
}

// ---------------- fused kernel: circuit + slice of the linear layer ----------------
__global__ __launch_bounds__(256, 4) void qcirc_kernel(const float* __restrict__ x,
                                                       const float* __restrict__ qp,
                                                       const float* __restrict__ lw,
                                                       const float* __restrict__ lb,
                                                       float* __restrict__ out) {
  __shared__ f32x2 st[DIM];         // 32 KB state at swizzled index A12(q)
  __shared__ f32x2 gAB[24][2];      // (u00,u01) per fused gate, layers 1..2
  __shared__ f32x2 vq[NQ][2];       // per-qubit initial 2-vectors (layer 0 folded)

  const int tid = threadIdx.x;
  const int s = blockIdx.x >> 1;
  const int g = blockIdx.x & 1;

  // hoisted per-lane table loads + x row (hide latency under setup)
  unsigned lutr[6];
  #pragma unroll
  for (int i = 0; i < 6; ++i) lutr[i] = d_gtab.lut[i][tid];
  const unsigned sflo = d_gtab.sflo[tid];
  float xr[NQ];
  #pragma unroll
  for (int jj = 0; jj < 3; ++jj)
    *(float4*)&xr[jj * 4] = *(const float4*)&x[s * NQ + jj * 4];

  if (tid < 24) {
    const int li = tid / 12, y = tid % 12;
    const float* w = qp + g * 108 + (li + 1) * 36 + 3 * y;
    float2 U[4];
    fusedU(w[0], w[1], w[2], U);
    gAB[tid][0] = (f32x2){U[0].x, U[0].y};
    gAB[tid][1] = (f32x2){U[1].x, U[1].y};
  } else if (tid >= 64 && tid < 64 + NQ) {
    const int j = tid - 64;
    const float* w = qp + g * 108 + 3 * j;
    float2 U0[4];
    fusedU(w[0], w[1], w[2], U0);
    float cx, sx;
    sincosf(x[s * NQ + j] * 0.5f, &sx, &cx);
    vq[j][0] = (f32x2){U0[0].x * cx + U0[1].x * sx, U0[0].y * cx + U0[1].y * sx};
    vq[j][1] = (f32x2){U0[2].x * cx + U0[3].x * sx, U0[2].y * cx + U0[3].y * sx};
  }
  __syncthreads();

  // product state (layer 0 folded): e = r*256+tid lives at (r*0x111) ^ tid ^ (tid>>4)
  {
    const unsigned bt = (unsigned)tid ^ ((unsigned)tid >> 4);
    f32x2 low = vq[11][tid & 1];
    #pragma unroll
    for (int p = 1; p < 8; ++p) low = pcmul(low, vq[11 - p][(tid >> p) & 1]);
    #pragma unroll
    for (int r = 0; r < 16; ++r) {
      f32x2 h = vq[3][r & 1];
      h = pcmul(h, vq[2][(r >> 1) & 1]);
      h = pcmul(h, vq[1][(r >> 2) & 1]);
      h = pcmul(h, vq[0][(r >> 3) & 1]);
      st[(r * 0x111) ^ bt] = pcmul(low, h);
    }
  }

  __syncthreads(); do_pass<0>(st, gAB, lutr[0]);
  __syncthreads(); do_pass<1>(st, gAB, lutr[1]);
  __syncthreads(); do_pass<2>(st, gAB, lutr[2]);
  __syncthreads(); do_pass<3>(st, gAB, lutr[3]);
  __syncthreads(); do_pass<4>(st, gAB, lutr[4]);
  __syncthreads(); do_pass<5>(st, gAB, lutr[5]);
  __syncthreads();

  // output gather with final ring^3 folded
  float* ob = out + (size_t)s * (NGEN * DIM) + (size_t)g * DIM;
  #pragma unroll
  for (int k = 0; k < 16; ++k) {
    const f32x2 a = st[(sflo ^ (unsigned)h_gtab.sfhi[k])];
    ob[k * 256 + tid] = a.x * a.x + a.y * a.y;
  }

  // fused linear slice: dims [g*2048, (g+1)*2048) of converted_x for sample s
  float* o2 = out + (size_t)BATCH * NGEN * DIM + (size_t)s * DIM;
  #pragma unroll
  for (int it = 0; it < 2; ++it) {
    const int d0 = g * 2048 + it * 1024 + tid * 4;
    const float4 b4 = *(const float4*)&lb[d0];
    float4 r;
    float* rp = &r.x;
    const float* bp = &b4.x;
    #pragma unroll
    for (int dd = 0; dd < 4; ++dd) {
      float acc = bp[dd];
      const float* wrow = lw + (size_t)(d0 + dd) * NQ;
      #pragma unroll
      for (int j = 0; j < NQ; ++j) acc = fmaf(xr[j], wrow[j], acc);
      rp[dd] = acc * 5.0f;
    }
    *(float4*)&o2[d0] = r;
  }
}

extern "C" void kernel_launch(void* const* d_in, const int* in_sizes, int n_in,
                              void* d_out, int out_size, void* d_ws, size_t ws_size,
                              hipStream_t stream) {
  const float* x    = (const float*)d_in[0];
  const float* qp   = (const float*)d_in[1];
  const float* linw = (const float*)d_in[2];
  const float* linb = (const float*)d_in[3];
  float* out = (float*)d_out;

  qcirc_kernel<<<BATCH * NGEN, 256, 0, stream>>>(x, qp, linw, linb, out);
}